// Round 1
// baseline (229.717 us; speedup 1.0000x reference)
//
#include <hip/hip_runtime.h>
#include <math.h>

#define ROW_LEN 4096
#define NROWS   8192
#define BLOCK   256
// 4096 floats / 256 threads = 16 floats/thread = 4 float4/thread
#define V4_PER_THREAD 4

__global__ __launch_bounds__(BLOCK) void masked_softmax_kernel(
    const float* __restrict__ X,
    const int* __restrict__ N,
    float* __restrict__ out)
{
    const int row = blockIdx.x;
    const int tid = threadIdx.x;
    const int n   = N[row];   // valid length in [1, ROW_LEN]

    const float4* __restrict__ Xr = (const float4*)(X + (size_t)row * ROW_LEN);
    float4* __restrict__ Or       = (float4*)(out + (size_t)row * ROW_LEN);

    // ---- load entire row into registers (coalesced float4) ----
    float4 v[V4_PER_THREAD];
    float m = -INFINITY;
    #pragma unroll
    for (int i = 0; i < V4_PER_THREAD; i++) {
        const int idx = i * BLOCK + tid;     // float4 index within row
        v[i] = Xr[idx];
        const int col = idx * 4;
        if (col + 0 < n) m = fmaxf(m, v[i].x);
        if (col + 1 < n) m = fmaxf(m, v[i].y);
        if (col + 2 < n) m = fmaxf(m, v[i].z);
        if (col + 3 < n) m = fmaxf(m, v[i].w);
    }

    // ---- block-wide max reduction (wave=64 shuffle, then LDS across 4 waves) ----
    #pragma unroll
    for (int off = 32; off > 0; off >>= 1)
        m = fmaxf(m, __shfl_down(m, off, 64));

    __shared__ float s_red[4];
    const int wave = tid >> 6;
    const int lane = tid & 63;
    if (lane == 0) s_red[wave] = m;
    __syncthreads();
    if (tid == 0) {
        s_red[0] = fmaxf(fmaxf(s_red[0], s_red[1]), fmaxf(s_red[2], s_red[3]));
    }
    __syncthreads();
    m = s_red[0];
    __syncthreads();   // s_red reused below for sum

    // ---- exp + masked sum ----
    float s = 0.0f;
    #pragma unroll
    for (int i = 0; i < V4_PER_THREAD; i++) {
        const int idx = i * BLOCK + tid;
        const int col = idx * 4;
        v[i].x = __expf(v[i].x - m);
        v[i].y = __expf(v[i].y - m);
        v[i].z = __expf(v[i].z - m);
        v[i].w = __expf(v[i].w - m);
        if (col + 0 < n) s += v[i].x;
        if (col + 1 < n) s += v[i].y;
        if (col + 2 < n) s += v[i].z;
        if (col + 3 < n) s += v[i].w;
    }

    #pragma unroll
    for (int off = 32; off > 0; off >>= 1)
        s += __shfl_down(s, off, 64);
    if (lane == 0) s_red[wave] = s;
    __syncthreads();
    if (tid == 0) {
        s_red[0] = (s_red[0] + s_red[1]) + (s_red[2] + s_red[3]);
    }
    __syncthreads();
    const float inv = 1.0f / s_red[0];

    // ---- write: mask * exp / sum  (explicit zeros past n) ----
    #pragma unroll
    for (int i = 0; i < V4_PER_THREAD; i++) {
        const int idx = i * BLOCK + tid;
        const int col = idx * 4;
        float4 o;
        o.x = (col + 0 < n) ? v[i].x * inv : 0.0f;
        o.y = (col + 1 < n) ? v[i].y * inv : 0.0f;
        o.z = (col + 2 < n) ? v[i].z * inv : 0.0f;
        o.w = (col + 3 < n) ? v[i].w * inv : 0.0f;
        Or[idx] = o;
    }
}

extern "C" void kernel_launch(void* const* d_in, const int* in_sizes, int n_in,
                              void* d_out, int out_size, void* d_ws, size_t ws_size,
                              hipStream_t stream) {
    const float* X = (const float*)d_in[0];
    const int*   N = (const int*)d_in[1];
    float* out = (float*)d_out;
    masked_softmax_kernel<<<NROWS, BLOCK, 0, stream>>>(X, N, out);
}

// Round 3
// 223.266 us; speedup vs baseline: 1.0289x; 1.0289x over previous
//
#include <hip/hip_runtime.h>
#include <math.h>

#define ROW_LEN 4096
#define NROWS   8192
#define BLOCK   256
#define WAVES_PER_BLOCK (BLOCK / 64)
// 4096 floats / 64 lanes = 64 floats/lane = 16 float4/lane
#define F4_PER_LANE 16

// native clang vector type — accepted by __builtin_nontemporal_load/store
typedef float vf4 __attribute__((ext_vector_type(4)));

__global__ __launch_bounds__(BLOCK) void masked_softmax_wave(
    const float* __restrict__ X,
    const int* __restrict__ N,
    float* __restrict__ out)
{
    const int wave = threadIdx.x >> 6;
    const int lane = threadIdx.x & 63;
    const int row  = blockIdx.x * WAVES_PER_BLOCK + wave;

    // n is wave-uniform (one row per wave) — force it scalar
    const int n = __builtin_amdgcn_readfirstlane(N[row]);

    const vf4* __restrict__ Xr = (const vf4*)(X + (size_t)row * ROW_LEN);
    vf4* __restrict__ Or       = (vf4*)(out + (size_t)row * ROW_LEN);

    // ---- load entire row into registers (coalesced float4, streamed) ----
    vf4 v[F4_PER_LANE];
    #pragma unroll
    for (int j = 0; j < F4_PER_LANE; j++) {
        v[j] = __builtin_nontemporal_load(&Xr[lane + 64 * j]);
    }

    // ---- masked max over registers ----
    float m = -INFINITY;
    #pragma unroll
    for (int j = 0; j < F4_PER_LANE; j++) {
        const int col = 4 * (lane + 64 * j);
        m = fmaxf(m, (col + 0 < n) ? v[j].x : -INFINITY);
        m = fmaxf(m, (col + 1 < n) ? v[j].y : -INFINITY);
        m = fmaxf(m, (col + 2 < n) ? v[j].z : -INFINITY);
        m = fmaxf(m, (col + 3 < n) ? v[j].w : -INFINITY);
    }
    // wave-wide max, butterfly (no LDS, no barrier)
    #pragma unroll
    for (int off = 1; off < 64; off <<= 1)
        m = fmaxf(m, __shfl_xor(m, off, 64));

    // ---- exp, mask folded in (v[] becomes masked exp), masked sum ----
    float s = 0.0f;
    #pragma unroll
    for (int j = 0; j < F4_PER_LANE; j++) {
        const int col = 4 * (lane + 64 * j);
        float ex = __expf(v[j].x - m);
        float ey = __expf(v[j].y - m);
        float ez = __expf(v[j].z - m);
        float ew = __expf(v[j].w - m);
        ex = (col + 0 < n) ? ex : 0.0f;
        ey = (col + 1 < n) ? ey : 0.0f;
        ez = (col + 2 < n) ? ez : 0.0f;
        ew = (col + 3 < n) ? ew : 0.0f;
        v[j].x = ex; v[j].y = ey; v[j].z = ez; v[j].w = ew;
        s += (ex + ey) + (ez + ew);
    }
    // wave-wide sum, butterfly
    #pragma unroll
    for (int off = 1; off < 64; off <<= 1)
        s += __shfl_xor(s, off, 64);

    const float inv = 1.0f / s;

    // ---- store: pure multiply, streamed ----
    #pragma unroll
    for (int j = 0; j < F4_PER_LANE; j++) {
        vf4 o;
        o.x = v[j].x * inv;
        o.y = v[j].y * inv;
        o.z = v[j].z * inv;
        o.w = v[j].w * inv;
        __builtin_nontemporal_store(o, &Or[lane + 64 * j]);
    }
}

extern "C" void kernel_launch(void* const* d_in, const int* in_sizes, int n_in,
                              void* d_out, int out_size, void* d_ws, size_t ws_size,
                              hipStream_t stream) {
    const float* X = (const float*)d_in[0];
    const int*   N = (const int*)d_in[1];
    float* out = (float*)d_out;
    masked_softmax_wave<<<NROWS / WAVES_PER_BLOCK, BLOCK, 0, stream>>>(X, N, out);
}